// Round 9
// baseline (2402.034 us; speedup 1.0000x reference)
//
#include <hip/hip_runtime.h>

typedef float f2 __attribute__((ext_vector_type(2)));

#define NB 4
#define NN 4096
#define KNB 16
#define NS 1024
#define M1TOT (NB*NN*KNB)   // 262144
#define EPSBN 1e-5f
#define FPS_SPLIT 511       // kS1 runs iters [0,511); kS2 runs [511,1023)

// ---- module-scope scratch (fully rewritten every call; no ws_size assumption)
__device__ __align__(16) float g_h1[(size_t)M1TOT*128];   // 134 MB spilled layer-1 pre-activations
__device__ __align__(16) int   g_nbr[NB*NN*KNB];
__device__ __align__(16) float g_fps_rd[NB][NN];
__device__ unsigned g_fps_sel[NB][256];
__device__ int   g_fps_last[NB];
__device__ int   g_cent[NB][NS];
__device__ float g_sum1[128], g_sq1[128], g_sum2[128], g_sq2[128];
__device__ __align__(16) float g_hminN[NB*NN*128];        // 8 MB per-node h2 min
__device__ __align__(16) float g_hmaxN[NB*NN*128];        // 8 MB per-node h2 max

struct __align__(16) FpsSm {
    float spx[NN], spy[NN], spz[NN];
    float sv[2][4]; int sj[2][4];
    int   cnts[256];
};
struct __align__(16) G1Sm {
    float  xls[64*68];
    float4 wlsA[68*16], wlsB[68*16];
    float  redS[512], redQ[512];
};
struct __align__(16) G2Sm {
    float  yls[64*132];
    float4 w2A[32*16], w2B[32*16];
    float  scs[128], shs[128];
    float  redS[512], redQ[512];
};
// kPre scan phase needs the 48KB point cache; merge phase reuses the same LDS for 32KB of keys
union KnnSm {
    struct { float spx[NN], spy[NN], spz[NN]; } p;
    unsigned long long pairs[32*128];             // 32 queries x (8 chunks x 16 keys)
};

// ================= FPS chunk: 256 threads, 16 pts/thread (f2 packed), checkpointed ==========
__device__ __forceinline__ void fps_chunk(const float* __restrict__ pos, float* __restrict__ out,
                                          FpsSm* sm, int b, int t, int it0, int it1,
                                          bool first, bool last)
{
#pragma clang fp contract(off)
    const float* pb = pos + b*NN*3;
    for (int i = t; i < NN; i += 256) { sm->spx[i]=pb[3*i]; sm->spy[i]=pb[3*i+1]; sm->spz[i]=pb[3*i+2]; }
    __syncthreads();
    f2 rx[8], ry[8], rz[8], rd[8];
    #pragma unroll
    for (int p=0;p<8;p++){
        int j = (t<<4) + 2*p;
        rx[p] = *(const f2*)&sm->spx[j];
        ry[p] = *(const f2*)&sm->spy[j];
        rz[p] = *(const f2*)&sm->spz[j];
    }
    unsigned sel; int j2;
    if (first) {
        #pragma unroll
        for (int p=0;p<8;p++) rd[p] = (f2){1e10f, 1e10f};
        sel = (t==0) ? 1u : 0u;              // node 0 is always selected
        j2 = 0;
    } else {
        #pragma unroll
        for (int u=0;u<4;u++){
            float4 ld = *(const float4*)&g_fps_rd[b][(t<<4)+(u<<2)];
            rd[2*u]   = (f2){ld.x, ld.y};
            rd[2*u+1] = (f2){ld.z, ld.w};
        }
        sel = g_fps_sel[b][t];
        j2  = g_fps_last[b];
    }
    float cx = sm->spx[j2], cy = sm->spy[j2], cz = sm->spz[j2];

    for (int it = it0; it < it1; ++it) {
        const int par = it & 1;
        const f2 c2x = {cx,cx}, c2y = {cy,cy}, c2z = {cz,cz};
        #pragma unroll
        for (int p=0;p<8;p++){
            f2 dx = rx[p]-c2x, dy = ry[p]-c2y, dz = rz[p]-c2z;
            f2 m0 = dx*dx, m1 = dy*dy, m2 = dz*dz;
            f2 a0 = m0 + m1;
            f2 d  = a0 + m2;                 // exact (dx^2+dy^2)+dz^2, contract off
            rd[p] = __builtin_elementwise_min(rd[p], d);
        }
        // local max tree (packed)
        f2 t0 = __builtin_elementwise_max(rd[0], rd[1]);
        f2 t1 = __builtin_elementwise_max(rd[2], rd[3]);
        f2 t2 = __builtin_elementwise_max(rd[4], rd[5]);
        f2 t3 = __builtin_elementwise_max(rd[6], rd[7]);
        t0 = __builtin_elementwise_max(t0, t1);
        t2 = __builtin_elementwise_max(t2, t3);
        t0 = __builtin_elementwise_max(t0, t2);
        float wv = fmaxf(t0.x, t0.y);
        // wave max, value only (6 cross-lane ops)
        #pragma unroll
        for (int m=1;m<64;m<<=1) wv = fmaxf(wv, __shfl_xor(wv, m));
        // lowest local index equal to wave max (reverse scan -> lowest wins)
        int lj = 0x7fffffff;
        #pragma unroll
        for (int p=7;p>=0;p--){
            lj = (rd[p].y == wv) ? ((t<<4)+2*p+1) : lj;
            lj = (rd[p].x == wv) ? ((t<<4)+2*p)   : lj;
        }
        // lanes cover ascending index ranges: first matching lane = lowest global index
        unsigned long long mk = __ballot(lj != 0x7fffffff);
        int src = __ffsll(mk) - 1;
        int bj = __shfl(lj, src);
        if ((t & 63) == 0) { sm->sv[par][t>>6] = wv; sm->sj[par][t>>6] = bj; }
        __syncthreads();     // single barrier/iter; parity double-buffered slots
        float v = sm->sv[par][0]; int jn = sm->sj[par][0];
        #pragma unroll
        for (int w=1;w<4;w++){
            float ov = sm->sv[par][w]; int oj = sm->sj[par][w];
            if (ov > v || (ov == v && oj < jn)) { v = ov; jn = oj; }
        }
        j2 = jn;
        cx = sm->spx[j2]; cy = sm->spy[j2]; cz = sm->spz[j2];
        unsigned rel = (unsigned)(j2 - (t<<4));
        if (rel < 16u) sel |= (1u << rel);
    }

    if (!last) {
        #pragma unroll
        for (int u=0;u<4;u++){
            float4 st = {rd[2*u].x, rd[2*u].y, rd[2*u+1].x, rd[2*u+1].y};
            *(float4*)&g_fps_rd[b][(t<<4)+(u<<2)] = st;
        }
        g_fps_sel[b][t] = sel;
        if (t == 0) g_fps_last[b] = j2;
    } else {
        // ordered compaction (ascending node index == reference's sorted centroids)
        sm->cnts[t] = (int)__popc(sel);
        __syncthreads();
        if (t == 0) { int run = 0; for (int i=0;i<256;i++){ int c = sm->cnts[i]; sm->cnts[i] = run; run += c; } }
        __syncthreads();
        int base = sm->cnts[t];
        #pragma unroll
        for (int i=0;i<16;i++){
            int j = (t<<4)+i;
            if (sel & (1u<<i)) {
                g_cent[b][base] = j;
                float* po = out + (size_t)((b<<10)+base)*3;
                po[0]=sm->spx[j]; po[1]=sm->spy[j]; po[2]=sm->spz[j];
                base++;
            }
        }
    }
}

// exact top-16 insert over u64 keys (dist_bits<<32 | idx): key order == (d, idx) lexicographic
__device__ __forceinline__ void key_ins(unsigned long long (&kk)[16], unsigned long long &wmax,
                                        unsigned long long key)
{
    unsigned long long m0 = kk[0]; int mj = 0;
    #pragma unroll
    for (int u=1;u<16;u++){ if (kk[u] > m0){ m0 = kk[u]; mj = u; } }
    #pragma unroll
    for (int u=0;u<16;u++){ if (u == mj) kk[u] = key; }
    unsigned long long w = kk[0];
    #pragma unroll
    for (int u=1;u<16;u++) w = (kk[u] > w) ? kk[u] : w;
    wmax = w;
}

// ===== kPre: blocks 0-511 split-scan KNN (8 lanes/query, 32 queries/block), block 512 zero ===
__global__ __launch_bounds__(256, 1) void kPre(const float* __restrict__ pos)
{
    __shared__ KnnSm sm;
    const int blk = blockIdx.x, t = threadIdx.x;
    if (blk >= 512) {
        if (t < 128) { g_sum1[t]=0.f; g_sq1[t]=0.f; g_sum2[t]=0.f; g_sq2[t]=0.f; }
        return;
    }
    const int b = blk >> 7;                    // 128 blocks per batch
    const int qloc = t >> 3, tq = t & 7;
    const int q = ((blk & 127) << 5) + qloc;
    const float* pb = pos + b*NN*3;
    for (int i = t; i < NN; i += 256) { sm.p.spx[i]=pb[3*i]; sm.p.spy[i]=pb[3*i+1]; sm.p.spz[i]=pb[3*i+2]; }
    __syncthreads();
    const float qx = sm.p.spx[q], qy = sm.p.spy[q], qz = sm.p.spz[q];
    unsigned long long kk[16];
    #pragma unroll
    for (int u=0;u<16;u++) kk[u] = ~0ULL;
    unsigned long long wmax = ~0ULL;
    const int j0 = tq << 9;                    // 512-candidate chunk per lane
    for (int j = j0; j < j0 + 512; ++j) {
        float dx = sm.p.spx[j]-qx, dy = sm.p.spy[j]-qy, dz = sm.p.spz[j]-qz;
        float d = __fadd_rn(__fadd_rn(__fmul_rn(dx,dx),__fmul_rn(dy,dy)),__fmul_rn(dz,dz));
        unsigned long long key = ((unsigned long long)__float_as_uint(d) << 32) | (unsigned)j;
        if (key < wmax) key_ins(kk, wmax, key);
    }
    __syncthreads();                           // scan done; LDS points no longer needed
    #pragma unroll
    for (int u=0;u<16;u++) sm.pairs[(qloc<<7) + (tq<<4) + u] = kk[u];
    __syncthreads();
    if (tq == 0) {                             // merge 128 partial keys -> exact global top-16
        unsigned long long kk2[16];
        #pragma unroll
        for (int u=0;u<16;u++) kk2[u] = ~0ULL;
        unsigned long long wm2 = ~0ULL;
        for (int e = 0; e < 128; ++e) {
            unsigned long long key = sm.pairs[(qloc<<7) + e];
            if (key < wm2) key_ins(kk2, wm2, key);
        }
        int* dst = g_nbr + ((size_t)(b*NN + q) << 4);
        #pragma unroll
        for (int u=0;u<16;u++) dst[u] = (int)(kk2[u] & 0xffffffffu);
    }
}

// ================= kS1: blocks 0-3 FPS [0,511); blocks 4..4099 GEMM1 + stats + h1 spill =====
__global__ __launch_bounds__(256, 1) void kS1(const float* __restrict__ feat, const float* __restrict__ pos,
                                              const float* __restrict__ W1, const float* __restrict__ b1)
{
    __shared__ union { FpsSm f; G1Sm g; } sm;
    const int blk = blockIdx.x, t = threadIdx.x;
    if (blk < 4) { fps_chunk(pos, nullptr, &sm.f, blk, t, 0, FPS_SPLIT, true, false); return; }
    const int gb = blk - 4;
    const int b = gb >> 10, nb = (gb & 1023) << 2;

    // stage W1 -> two float4 arrays [row 0..67][cg], row permuted (feat 0..63, rel 64..66, 67 zero)
    for (int e = t; e < 128*67; e += 256) {
        int co = e / 67, ci = e - co*67;
        int row = (ci < 3) ? (64 + ci) : (ci - 3);
        int cgd = co >> 3, h = co & 7;
        float w = W1[e];
        if (h < 4) ((float*)&sm.g.wlsA[row*16 + cgd])[h]   = w;
        else       ((float*)&sm.g.wlsB[row*16 + cgd])[h-4] = w;
    }
    if (t < 64) { ((float*)&sm.g.wlsA[67*16])[t] = 0.f; ((float*)&sm.g.wlsB[67*16])[t] = 0.f; }
    // gather x: 64 samples (4 nodes x 16 nbrs) x 68
    {
        const int s = t >> 2, h = t & 3;
        const int n = nb + (s >> 4), k = s & 15;
        const int gq = b*NN + n;
        const int idx = g_nbr[(gq << 4) + k];
        const float* fr = feat + ((size_t)(b*NN + idx) << 6) + (h << 4);
        float* xr = sm.g.xls + s*68 + (h << 4);
        #pragma unroll
        for (int u=0;u<4;u++) ((float4*)xr)[u] = ((const float4*)fr)[u];
        if (h == 0) {
            const float* pn = pos + (size_t)gq*3;
            const float* pi = pos + (size_t)(b*NN + idx)*3;
            sm.g.xls[s*68 + 64] = pi[0]-pn[0];
            sm.g.xls[s*68 + 65] = pi[1]-pn[1];
            sm.g.xls[s*68 + 66] = pi[2]-pn[2];
            sm.g.xls[s*68 + 67] = 0.f;
        }
    }
    __syncthreads();
    const int cg = t & 15, sg = t >> 4, w = t >> 6;
    float acc[4][8];
    #pragma unroll
    for (int r=0;r<4;r++)
        #pragma unroll
        for (int c=0;c<8;c++) acc[r][c] = 0.f;
    for (int c4 = 0; c4 < 17; ++c4) {
        float4 wA[4], wB[4];
        #pragma unroll
        for (int ii=0;ii<4;ii++){ wA[ii] = sm.g.wlsA[(4*c4+ii)*16 + cg]; wB[ii] = sm.g.wlsB[(4*c4+ii)*16 + cg]; }
        #pragma unroll
        for (int r=0;r<4;r++){
            float4 xv = *(const float4*)&sm.g.xls[(sg + (r<<4))*68 + (c4<<2)];
            #pragma unroll
            for (int ii=0;ii<4;ii++){
                float x = (ii==0)?xv.x:(ii==1)?xv.y:(ii==2)?xv.z:xv.w;
                acc[r][0] = fmaf(x, wA[ii].x, acc[r][0]);
                acc[r][1] = fmaf(x, wA[ii].y, acc[r][1]);
                acc[r][2] = fmaf(x, wA[ii].z, acc[r][2]);
                acc[r][3] = fmaf(x, wA[ii].w, acc[r][3]);
                acc[r][4] = fmaf(x, wB[ii].x, acc[r][4]);
                acc[r][5] = fmaf(x, wB[ii].y, acc[r][5]);
                acc[r][6] = fmaf(x, wB[ii].z, acc[r][6]);
                acc[r][7] = fmaf(x, wB[ii].w, acc[r][7]);
            }
        }
    }
    // h1 = acc + b1 ; stats ; spill to g_h1
    float4 bA = *(const float4*)&b1[cg<<3];
    float4 bB = *(const float4*)&b1[(cg<<3)+4];
    float h1v[4][8];
    #pragma unroll
    for (int r=0;r<4;r++){
        h1v[r][0]=acc[r][0]+bA.x; h1v[r][1]=acc[r][1]+bA.y; h1v[r][2]=acc[r][2]+bA.z; h1v[r][3]=acc[r][3]+bA.w;
        h1v[r][4]=acc[r][4]+bB.x; h1v[r][5]=acc[r][5]+bB.y; h1v[r][6]=acc[r][6]+bB.z; h1v[r][7]=acc[r][7]+bB.w;
    }
    #pragma unroll
    for (int c=0;c<8;c++){
        const int ch = (cg<<3)+c;
        float ls=0.f, lq=0.f;
        #pragma unroll
        for (int r=0;r<4;r++){ float h1 = h1v[r][c]; ls += h1; lq = fmaf(h1,h1,lq); }
        ls += __shfl_xor(ls,16); ls += __shfl_xor(ls,32);
        lq += __shfl_xor(lq,16); lq += __shfl_xor(lq,32);
        if ((sg & 3) == 0) { sm.g.redS[w*128 + ch] = ls; sm.g.redQ[w*128 + ch] = lq; }
    }
    #pragma unroll
    for (int r=0;r<4;r++){
        const int gs = (b*NN + nb + r)*16 + sg;
        float4 o0 = {h1v[r][0],h1v[r][1],h1v[r][2],h1v[r][3]};
        float4 o1 = {h1v[r][4],h1v[r][5],h1v[r][6],h1v[r][7]};
        *(float4*)&g_h1[(size_t)gs*128 + (cg<<3)]     = o0;
        *(float4*)&g_h1[(size_t)gs*128 + (cg<<3) + 4] = o1;
    }
    __syncthreads();
    if (t < 128) {
        float s = sm.g.redS[t] + sm.g.redS[128+t] + sm.g.redS[256+t] + sm.g.redS[384+t];
        float q = sm.g.redQ[t] + sm.g.redQ[128+t] + sm.g.redQ[256+t] + sm.g.redQ[384+t];
        atomicAdd(&g_sum1[t], s);
        atomicAdd(&g_sq1[t], q);
    }
}

// ================= kS2: blocks 0-3 FPS [511,1023)+finish; blocks 4..4099 BN1+GEMM2 ==========
__global__ __launch_bounds__(256, 1) void kS2(const float* __restrict__ pos, float* __restrict__ out,
        const float* __restrict__ W2, const float* __restrict__ b2,
        const float* __restrict__ gamma1, const float* __restrict__ beta1)
{
    __shared__ union { FpsSm f; G2Sm g; } sm;
    const int blk = blockIdx.x, t = threadIdx.x;
    if (blk < 4) { fps_chunk(pos, out, &sm.f, blk, t, FPS_SPLIT, NS-1, false, true); return; }
    const int gb = blk - 4;
    const int b = gb >> 10, nb = (gb & 1023) << 2;
    if (t < 128) {
        const float inv = 1.f/(float)M1TOT;
        float mu  = g_sum1[t]*inv;
        float var = g_sq1[t]*inv - mu*mu;
        float sc  = gamma1[t]*rsqrtf(var + EPSBN);
        sm.g.scs[t] = sc; sm.g.shs[t] = beta1[t] - mu*sc;
    }
    __syncthreads();
    // load h1 tile, BN1+ReLU, write y to LDS [64][132]
    {
        const float* hsrc = g_h1 + (size_t)((b*NN + nb)*16)*128;
        const int ch0 = (4*t) & 127;
        float4 sc4 = *(const float4*)&sm.g.scs[ch0];
        float4 sh4 = *(const float4*)&sm.g.shs[ch0];
        #pragma unroll
        for (int j=0;j<8;j++){
            int f = j*1024 + 4*t;
            float4 v = *(const float4*)&hsrc[f];
            int s = f >> 7;
            float4 yv;
            yv.x = fmaxf(0.f, fmaf(v.x, sc4.x, sh4.x));
            yv.y = fmaxf(0.f, fmaf(v.y, sc4.y, sh4.y));
            yv.z = fmaxf(0.f, fmaf(v.z, sc4.z, sh4.z));
            yv.w = fmaxf(0.f, fmaf(v.w, sc4.w, sh4.w));
            *(float4*)&sm.g.yls[s*132 + ch0] = yv;
        }
    }
    const int cg = t & 15, sg = t >> 4, w = t >> 6;
    float acc2[4][8];
    #pragma unroll
    for (int r=0;r<4;r++)
        #pragma unroll
        for (int c=0;c<8;c++) acc2[r][c]=0.f;
    for (int kc = 0; kc < 4; ++kc) {
        for (int e = t; e < 4096; e += 256) {     // stage W2[:, kc*32..+32) transposed, split A/B
            int d = e >> 5, kk = e & 31;
            float wv = W2[(d << 7) + (kc<<5) + kk];
            int cgd = d >> 3, h = d & 7;
            if (h < 4) ((float*)&sm.g.w2A[kk*16 + cgd])[h]   = wv;
            else       ((float*)&sm.g.w2B[kk*16 + cgd])[h-4] = wv;
        }
        __syncthreads();
        #pragma unroll
        for (int c4=0;c4<8;c4++){
            float4 wA[4], wB[4];
            #pragma unroll
            for (int ii=0;ii<4;ii++){ wA[ii] = sm.g.w2A[(4*c4+ii)*16 + cg]; wB[ii] = sm.g.w2B[(4*c4+ii)*16 + cg]; }
            #pragma unroll
            for (int r=0;r<4;r++){
                float4 yv = *(const float4*)&sm.g.yls[((sg<<2)+r)*132 + (kc<<5) + (c4<<2)];
                #pragma unroll
                for (int ii=0;ii<4;ii++){
                    float y = (ii==0)?yv.x:(ii==1)?yv.y:(ii==2)?yv.z:yv.w;
                    acc2[r][0] = fmaf(y, wA[ii].x, acc2[r][0]);
                    acc2[r][1] = fmaf(y, wA[ii].y, acc2[r][1]);
                    acc2[r][2] = fmaf(y, wA[ii].z, acc2[r][2]);
                    acc2[r][3] = fmaf(y, wA[ii].w, acc2[r][3]);
                    acc2[r][4] = fmaf(y, wB[ii].x, acc2[r][4]);
                    acc2[r][5] = fmaf(y, wB[ii].y, acc2[r][5]);
                    acc2[r][6] = fmaf(y, wB[ii].z, acc2[r][6]);
                    acc2[r][7] = fmaf(y, wB[ii].w, acc2[r][7]);
                }
            }
        }
        __syncthreads();
    }
    // epilogue: h2 = acc2 + b2 ; stats2 ; per-NODE min/max over 16 neighbors
    const int node = nb + (sg >> 2);
    #pragma unroll
    for (int c=0;c<8;c++){
        const int ch = (cg<<3)+c;
        const float bb = b2[ch];
        float ls=0.f, lq=0.f, mn=3e38f, mx=-3e38f;
        #pragma unroll
        for (int r=0;r<4;r++){
            float h2 = acc2[r][c] + bb;
            ls += h2; lq = fmaf(h2,h2,lq);
            mn = fminf(mn,h2); mx = fmaxf(mx,h2);
        }
        ls += __shfl_xor(ls,16); ls += __shfl_xor(ls,32);
        lq += __shfl_xor(lq,16); lq += __shfl_xor(lq,32);
        if ((sg & 3) == 0) { sm.g.redS[w*128 + ch] = ls; sm.g.redQ[w*128 + ch] = lq; }
        float o;
        o = __shfl_xor(mn,16); mn = fminf(mn,o);
        o = __shfl_xor(mn,32); mn = fminf(mn,o);
        o = __shfl_xor(mx,16); mx = fmaxf(mx,o);
        o = __shfl_xor(mx,32); mx = fmaxf(mx,o);
        if ((sg & 3) == 0) {
            const int oo = ((b<<12)+node)*128 + ch;
            g_hminN[oo] = mn; g_hmaxN[oo] = mx;
        }
    }
    __syncthreads();
    if (t < 128) {
        float s = sm.g.redS[t] + sm.g.redS[128+t] + sm.g.redS[256+t] + sm.g.redS[384+t];
        float q = sm.g.redQ[t] + sm.g.redQ[128+t] + sm.g.redQ[256+t] + sm.g.redQ[384+t];
        atomicAdd(&g_sum2[t], s);
        atomicAdd(&g_sq2[t], q);
    }
}

// ================= kFinal: gather centroid nodes, BN2 affine + ReLU via min/max monotonicity ==
__global__ __launch_bounds__(256) void kFinal(const float* __restrict__ gamma2, const float* __restrict__ beta2,
                                              float* __restrict__ out)
{
    const int gid = blockIdx.x*256 + threadIdx.x;
    const int base = gid << 2;
    const int sl = base >> 7;                 // global slot 0..4095
    const int b = sl >> 10, slot = sl & 1023;
    const int ch0 = base & 127;
    const int node = g_cent[b][slot];
    const int src = ((b<<12)+node)*128 + ch0;
    const float inv = 1.f/(float)M1TOT;
    float4 mx = *(const float4*)&g_hmaxN[src];
    float4 mn = *(const float4*)&g_hminN[src];
    float4 o;
    #pragma unroll
    for (int c=0;c<4;c++){
        int ch = ch0 + c;
        float mu = g_sum2[ch]*inv, var = g_sq2[ch]*inv - mu*mu;
        float sc = gamma2[ch]*rsqrtf(var+EPSBN), sh = beta2[ch] - mu*sc;
        float hi = (c==0)?mx.x:(c==1)?mx.y:(c==2)?mx.z:mx.w;
        float lo = (c==0)?mn.x:(c==1)?mn.y:(c==2)?mn.z:mn.w;
        float v = fmaxf(0.f, fmaf((sc >= 0.f) ? hi : lo, sc, sh));
        if (c==0) o.x=v; else if (c==1) o.y=v; else if (c==2) o.z=v; else o.w=v;
    }
    *(float4*)&out[12288 + base] = o;
}

extern "C" void kernel_launch(void* const* d_in, const int* in_sizes, int n_in,
                              void* d_out, int out_size, void* d_ws, size_t ws_size,
                              hipStream_t stream)
{
    (void)in_sizes; (void)n_in; (void)d_ws; (void)ws_size; (void)out_size;
    const float* feat = (const float*)d_in[0];
    const float* pos  = (const float*)d_in[1];
    const float* W1   = (const float*)d_in[2];
    const float* b1   = (const float*)d_in[3];
    const float* g1   = (const float*)d_in[4];
    const float* be1  = (const float*)d_in[5];
    const float* W2   = (const float*)d_in[6];
    const float* b2   = (const float*)d_in[7];
    const float* g2   = (const float*)d_in[8];
    const float* be2  = (const float*)d_in[9];
    float* out = (float*)d_out;

    kPre  <<<dim3(513),  dim3(256), 0, stream>>>(pos);
    kS1   <<<dim3(4100), dim3(256), 0, stream>>>(feat, pos, W1, b1);
    kS2   <<<dim3(4100), dim3(256), 0, stream>>>(pos, out, W2, b2, g1, be1);
    kFinal<<<dim3(512),  dim3(256), 0, stream>>>(g2, be2, out);
}

// Round 10
// 1469.538 us; speedup vs baseline: 1.6346x; 1.6346x over previous
//
#include <hip/hip_runtime.h>

typedef float f2 __attribute__((ext_vector_type(2)));

#define NB 4
#define NN 4096
#define KNB 16
#define NS 1024
#define M1TOT (NB*NN*KNB)   // 262144
#define EPSBN 1e-5f
#define FPS_SPLIT 511       // kS1 runs iters [0,511); kS2 runs [511,1023)
#define PADN 4124           // 4096 + 4 pad per 512-chunk: conflict-free 8-chunk parallel scan

// ---- module-scope scratch (fully rewritten every call; no ws_size assumption)
__device__ __align__(16) float g_h1[(size_t)M1TOT*128];   // 134 MB spilled layer-1 pre-activations
__device__ __align__(16) int   g_nbr[NB*NN*KNB];
__device__ __align__(16) float g_fps_rd[NB][NN];
__device__ unsigned g_fps_sel[NB][256];
__device__ int   g_fps_last[NB];
__device__ int   g_cent[NB][NS];
__device__ float g_sum1[128], g_sq1[128], g_sum2[128], g_sq2[128];
__device__ __align__(16) float g_hminN[NB*NN*128];        // 8 MB per-node h2 min
__device__ __align__(16) float g_hmaxN[NB*NN*128];        // 8 MB per-node h2 max

struct __align__(16) FpsSm {
    float spx[NN], spy[NN], spz[NN];
    float sv[2][4]; int sj[2][4];
    int   cnts[256];
};
struct __align__(16) G1Sm {
    float  xls[64*68];
    float4 wlsA[68*16], wlsB[68*16];
    float  redS[512], redQ[512];
};
struct __align__(16) G2Sm {
    float  yls[64*132];
    float4 w2A[32*16], w2B[32*16];
    float  scs[128], shs[128];
    float  redS[512], redQ[512];
};
// kPre scan phase: padded point cache (49.5KB); merge phase reuses LDS for keys (stride 130)
union KnnSm {
    struct { float spx[PADN], spy[PADN], spz[PADN]; } p;
    unsigned long long pairs[32*130];
};

// ================= FPS chunk: 256 threads, 16 pts/thread (f2 packed), checkpointed ==========
__device__ __forceinline__ void fps_chunk(const float* __restrict__ pos, float* __restrict__ out,
                                          FpsSm* sm, int b, int t, int it0, int it1,
                                          bool first, bool last)
{
#pragma clang fp contract(off)
    const float* pb = pos + b*NN*3;
    for (int i = t; i < NN; i += 256) { sm->spx[i]=pb[3*i]; sm->spy[i]=pb[3*i+1]; sm->spz[i]=pb[3*i+2]; }
    __syncthreads();
    f2 rx[8], ry[8], rz[8], rd[8];
    #pragma unroll
    for (int p=0;p<8;p++){
        int j = (t<<4) + 2*p;
        rx[p] = *(const f2*)&sm->spx[j];
        ry[p] = *(const f2*)&sm->spy[j];
        rz[p] = *(const f2*)&sm->spz[j];
    }
    unsigned sel; int j2;
    if (first) {
        #pragma unroll
        for (int p=0;p<8;p++) rd[p] = (f2){1e10f, 1e10f};
        sel = (t==0) ? 1u : 0u;              // node 0 is always selected
        j2 = 0;
    } else {
        #pragma unroll
        for (int u=0;u<4;u++){
            float4 ld = *(const float4*)&g_fps_rd[b][(t<<4)+(u<<2)];
            rd[2*u]   = (f2){ld.x, ld.y};
            rd[2*u+1] = (f2){ld.z, ld.w};
        }
        sel = g_fps_sel[b][t];
        j2  = g_fps_last[b];
    }
    float cx = sm->spx[j2], cy = sm->spy[j2], cz = sm->spz[j2];

    for (int it = it0; it < it1; ++it) {
        const int par = it & 1;
        const f2 c2x = {cx,cx}, c2y = {cy,cy}, c2z = {cz,cz};
        #pragma unroll
        for (int p=0;p<8;p++){
            f2 dx = rx[p]-c2x, dy = ry[p]-c2y, dz = rz[p]-c2z;
            f2 m0 = dx*dx, m1 = dy*dy, m2 = dz*dz;
            f2 a0 = m0 + m1;
            f2 d  = a0 + m2;                 // exact (dx^2+dy^2)+dz^2, contract off
            rd[p] = __builtin_elementwise_min(rd[p], d);
        }
        // local max tree (packed)
        f2 t0 = __builtin_elementwise_max(rd[0], rd[1]);
        f2 t1 = __builtin_elementwise_max(rd[2], rd[3]);
        f2 t2 = __builtin_elementwise_max(rd[4], rd[5]);
        f2 t3 = __builtin_elementwise_max(rd[6], rd[7]);
        t0 = __builtin_elementwise_max(t0, t1);
        t2 = __builtin_elementwise_max(t2, t3);
        t0 = __builtin_elementwise_max(t0, t2);
        float wv = fmaxf(t0.x, t0.y);
        // wave max, value only (6 cross-lane ops)
        #pragma unroll
        for (int m=1;m<64;m<<=1) wv = fmaxf(wv, __shfl_xor(wv, m));
        // lowest local index equal to wave max (reverse scan -> lowest wins)
        int lj = 0x7fffffff;
        #pragma unroll
        for (int p=7;p>=0;p--){
            lj = (rd[p].y == wv) ? ((t<<4)+2*p+1) : lj;
            lj = (rd[p].x == wv) ? ((t<<4)+2*p)   : lj;
        }
        // lanes cover ascending index ranges: first matching lane = lowest global index
        unsigned long long mk = __ballot(lj != 0x7fffffff);
        int src = __ffsll(mk) - 1;
        int bj = __shfl(lj, src);
        if ((t & 63) == 0) { sm->sv[par][t>>6] = wv; sm->sj[par][t>>6] = bj; }
        __syncthreads();     // single barrier/iter; parity double-buffered slots
        float v = sm->sv[par][0]; int jn = sm->sj[par][0];
        #pragma unroll
        for (int w=1;w<4;w++){
            float ov = sm->sv[par][w]; int oj = sm->sj[par][w];
            if (ov > v || (ov == v && oj < jn)) { v = ov; jn = oj; }
        }
        j2 = jn;
        cx = sm->spx[j2]; cy = sm->spy[j2]; cz = sm->spz[j2];
        unsigned rel = (unsigned)(j2 - (t<<4));
        if (rel < 16u) sel |= (1u << rel);
    }

    if (!last) {
        #pragma unroll
        for (int u=0;u<4;u++){
            float4 st = {rd[2*u].x, rd[2*u].y, rd[2*u+1].x, rd[2*u+1].y};
            *(float4*)&g_fps_rd[b][(t<<4)+(u<<2)] = st;
        }
        g_fps_sel[b][t] = sel;
        if (t == 0) g_fps_last[b] = j2;
    } else {
        // ordered compaction (ascending node index == reference's sorted centroids)
        sm->cnts[t] = (int)__popc(sel);
        __syncthreads();
        if (t == 0) { int run = 0; for (int i=0;i<256;i++){ int c = sm->cnts[i]; sm->cnts[i] = run; run += c; } }
        __syncthreads();
        int base = sm->cnts[t];
        #pragma unroll
        for (int i=0;i<16;i++){
            int j = (t<<4)+i;
            if (sel & (1u<<i)) {
                g_cent[b][base] = j;
                float* po = out + (size_t)((b<<10)+base)*3;
                po[0]=sm->spx[j]; po[1]=sm->spy[j]; po[2]=sm->spz[j];
                base++;
            }
        }
    }
}

// u64 insert for the merge phase (key = dist_bits<<32 | idx, total order == (d, idx))
__device__ __forceinline__ void key_ins(unsigned long long (&kk)[16], unsigned long long &wmax,
                                        unsigned long long key)
{
    unsigned long long m0 = kk[0]; int mj = 0;
    #pragma unroll
    for (int u=1;u<16;u++){ if (kk[u] > m0){ m0 = kk[u]; mj = u; } }
    #pragma unroll
    for (int u=0;u<16;u++){ if (u == mj) kk[u] = key; }
    unsigned long long w = kk[0];
    #pragma unroll
    for (int u=1;u<16;u++) w = (kk[u] > w) ? kk[u] : w;
    wmax = w;
}

// ===== kPre: blocks 0-511 split-scan KNN (8 lanes/query, 32 queries/block), block 512 zero ===
// Scan: float insert over ascending-j chunk (strict < keeps lowest j on boundary ties -> exact
// 16 smallest (d,j) keys per chunk). Merge: u64 lexicographic over 8 exact partials -> exact.
__global__ __launch_bounds__(256, 1) void kPre(const float* __restrict__ pos)
{
    __shared__ KnnSm sm;
    const int blk = blockIdx.x, t = threadIdx.x;
    if (blk >= 512) {
        if (t < 128) { g_sum1[t]=0.f; g_sq1[t]=0.f; g_sum2[t]=0.f; g_sq2[t]=0.f; }
        return;
    }
    const int b = blk >> 7;                    // 128 blocks per batch
    const int qloc = t >> 3, tq = t & 7;
    const int q = ((blk & 127) << 5) + qloc;
    const float* pb = pos + b*NN*3;
    for (int i = t; i < NN; i += 256) {
        int l = i + ((i >> 9) << 2);           // padded slot
        sm.p.spx[l]=pb[3*i]; sm.p.spy[l]=pb[3*i+1]; sm.p.spz[l]=pb[3*i+2];
    }
    __syncthreads();
    const int lq = q + ((q >> 9) << 2);
    const float qx = sm.p.spx[lq], qy = sm.p.spy[lq], qz = sm.p.spz[lq];
    float bd[16]; int bi[16];
    #pragma unroll
    for (int u=0;u<16;u++){ bd[u]=3e38f; bi[u]=0; }
    float wmax = 3e38f;
    const int base = tq * 516;                 // padded chunk base: banks (4*tq+i)%32, distinct
    const int j0 = tq << 9;
    for (int i = 0; i < 512; ++i) {
        float dx = sm.p.spx[base+i]-qx, dy = sm.p.spy[base+i]-qy, dz = sm.p.spz[base+i]-qz;
        float d = __fadd_rn(__fadd_rn(__fmul_rn(dx,dx),__fmul_rn(dy,dy)),__fmul_rn(dz,dz));
        if (d < wmax) {                        // strict <: lowest j wins boundary ties
            float m0 = bd[0]; int mj = 0;
            #pragma unroll
            for (int u=1;u<16;u++){ if (bd[u] > m0) { m0 = bd[u]; mj = u; } }
            #pragma unroll
            for (int u=0;u<16;u++){ if (u == mj) { bd[u] = d; bi[u] = j0 + i; } }
            wmax = bd[0];
            #pragma unroll
            for (int u=1;u<16;u++) wmax = fmaxf(wmax, bd[u]);
        }
    }
    __syncthreads();                           // scan done; LDS points no longer needed
    #pragma unroll
    for (int u=0;u<16;u++)
        sm.pairs[qloc*130 + (tq<<4) + u] =
            ((unsigned long long)__float_as_uint(bd[u]) << 32) | (unsigned)bi[u];
    __syncthreads();
    if (tq == 0) {                             // merge 128 partial keys -> exact global top-16
        unsigned long long kk2[16];
        #pragma unroll
        for (int u=0;u<16;u++) kk2[u] = ~0ULL;
        unsigned long long wm2 = ~0ULL;
        for (int e = 0; e < 128; ++e) {
            unsigned long long key = sm.pairs[qloc*130 + e];
            if (key < wm2) key_ins(kk2, wm2, key);
        }
        int* dst = g_nbr + ((size_t)(b*NN + q) << 4);
        #pragma unroll
        for (int u=0;u<16;u++) dst[u] = (int)(kk2[u] & 0xffffffffu);
    }
}

// ================= kS1: blocks 0-3 FPS [0,511); blocks 4..4099 GEMM1 + stats + h1 spill =====
__global__ __launch_bounds__(256, 1) void kS1(const float* __restrict__ feat, const float* __restrict__ pos,
                                              const float* __restrict__ W1, const float* __restrict__ b1)
{
    __shared__ union { FpsSm f; G1Sm g; } sm;
    const int blk = blockIdx.x, t = threadIdx.x;
    if (blk < 4) { fps_chunk(pos, nullptr, &sm.f, blk, t, 0, FPS_SPLIT, true, false); return; }
    const int gb = blk - 4;
    const int b = gb >> 10, nb = (gb & 1023) << 2;

    // stage W1 -> two float4 arrays [row 0..67][cg], row permuted (feat 0..63, rel 64..66, 67 zero)
    for (int e = t; e < 128*67; e += 256) {
        int co = e / 67, ci = e - co*67;
        int row = (ci < 3) ? (64 + ci) : (ci - 3);
        int cgd = co >> 3, h = co & 7;
        float w = W1[e];
        if (h < 4) ((float*)&sm.g.wlsA[row*16 + cgd])[h]   = w;
        else       ((float*)&sm.g.wlsB[row*16 + cgd])[h-4] = w;
    }
    if (t < 64) { ((float*)&sm.g.wlsA[67*16])[t] = 0.f; ((float*)&sm.g.wlsB[67*16])[t] = 0.f; }
    // gather x: 64 samples (4 nodes x 16 nbrs) x 68
    {
        const int s = t >> 2, h = t & 3;
        const int n = nb + (s >> 4), k = s & 15;
        const int gq = b*NN + n;
        const int idx = g_nbr[(gq << 4) + k];
        const float* fr = feat + ((size_t)(b*NN + idx) << 6) + (h << 4);
        float* xr = sm.g.xls + s*68 + (h << 4);
        #pragma unroll
        for (int u=0;u<4;u++) ((float4*)xr)[u] = ((const float4*)fr)[u];
        if (h == 0) {
            const float* pn = pos + (size_t)gq*3;
            const float* pi = pos + (size_t)(b*NN + idx)*3;
            sm.g.xls[s*68 + 64] = pi[0]-pn[0];
            sm.g.xls[s*68 + 65] = pi[1]-pn[1];
            sm.g.xls[s*68 + 66] = pi[2]-pn[2];
            sm.g.xls[s*68 + 67] = 0.f;
        }
    }
    __syncthreads();
    const int cg = t & 15, sg = t >> 4, w = t >> 6;
    float acc[4][8];
    #pragma unroll
    for (int r=0;r<4;r++)
        #pragma unroll
        for (int c=0;c<8;c++) acc[r][c] = 0.f;
    for (int c4 = 0; c4 < 17; ++c4) {
        float4 wA[4], wB[4];
        #pragma unroll
        for (int ii=0;ii<4;ii++){ wA[ii] = sm.g.wlsA[(4*c4+ii)*16 + cg]; wB[ii] = sm.g.wlsB[(4*c4+ii)*16 + cg]; }
        #pragma unroll
        for (int r=0;r<4;r++){
            float4 xv = *(const float4*)&sm.g.xls[(sg + (r<<4))*68 + (c4<<2)];
            #pragma unroll
            for (int ii=0;ii<4;ii++){
                float x = (ii==0)?xv.x:(ii==1)?xv.y:(ii==2)?xv.z:xv.w;
                acc[r][0] = fmaf(x, wA[ii].x, acc[r][0]);
                acc[r][1] = fmaf(x, wA[ii].y, acc[r][1]);
                acc[r][2] = fmaf(x, wA[ii].z, acc[r][2]);
                acc[r][3] = fmaf(x, wA[ii].w, acc[r][3]);
                acc[r][4] = fmaf(x, wB[ii].x, acc[r][4]);
                acc[r][5] = fmaf(x, wB[ii].y, acc[r][5]);
                acc[r][6] = fmaf(x, wB[ii].z, acc[r][6]);
                acc[r][7] = fmaf(x, wB[ii].w, acc[r][7]);
            }
        }
    }
    // h1 = acc + b1 ; stats ; spill to g_h1
    float4 bA = *(const float4*)&b1[cg<<3];
    float4 bB = *(const float4*)&b1[(cg<<3)+4];
    float h1v[4][8];
    #pragma unroll
    for (int r=0;r<4;r++){
        h1v[r][0]=acc[r][0]+bA.x; h1v[r][1]=acc[r][1]+bA.y; h1v[r][2]=acc[r][2]+bA.z; h1v[r][3]=acc[r][3]+bA.w;
        h1v[r][4]=acc[r][4]+bB.x; h1v[r][5]=acc[r][5]+bB.y; h1v[r][6]=acc[r][6]+bB.z; h1v[r][7]=acc[r][7]+bB.w;
    }
    #pragma unroll
    for (int c=0;c<8;c++){
        const int ch = (cg<<3)+c;
        float ls=0.f, lq=0.f;
        #pragma unroll
        for (int r=0;r<4;r++){ float h1 = h1v[r][c]; ls += h1; lq = fmaf(h1,h1,lq); }
        ls += __shfl_xor(ls,16); ls += __shfl_xor(ls,32);
        lq += __shfl_xor(lq,16); lq += __shfl_xor(lq,32);
        if ((sg & 3) == 0) { sm.g.redS[w*128 + ch] = ls; sm.g.redQ[w*128 + ch] = lq; }
    }
    #pragma unroll
    for (int r=0;r<4;r++){
        const int gs = (b*NN + nb + r)*16 + sg;
        float4 o0 = {h1v[r][0],h1v[r][1],h1v[r][2],h1v[r][3]};
        float4 o1 = {h1v[r][4],h1v[r][5],h1v[r][6],h1v[r][7]};
        *(float4*)&g_h1[(size_t)gs*128 + (cg<<3)]     = o0;
        *(float4*)&g_h1[(size_t)gs*128 + (cg<<3) + 4] = o1;
    }
    __syncthreads();
    if (t < 128) {
        float s = sm.g.redS[t] + sm.g.redS[128+t] + sm.g.redS[256+t] + sm.g.redS[384+t];
        float q = sm.g.redQ[t] + sm.g.redQ[128+t] + sm.g.redQ[256+t] + sm.g.redQ[384+t];
        atomicAdd(&g_sum1[t], s);
        atomicAdd(&g_sq1[t], q);
    }
}

// ================= kS2: blocks 0-3 FPS [511,1023)+finish; blocks 4..4099 BN1+GEMM2 ==========
__global__ __launch_bounds__(256, 1) void kS2(const float* __restrict__ pos, float* __restrict__ out,
        const float* __restrict__ W2, const float* __restrict__ b2,
        const float* __restrict__ gamma1, const float* __restrict__ beta1)
{
    __shared__ union { FpsSm f; G2Sm g; } sm;
    const int blk = blockIdx.x, t = threadIdx.x;
    if (blk < 4) { fps_chunk(pos, out, &sm.f, blk, t, FPS_SPLIT, NS-1, false, true); return; }
    const int gb = blk - 4;
    const int b = gb >> 10, nb = (gb & 1023) << 2;
    if (t < 128) {
        const float inv = 1.f/(float)M1TOT;
        float mu  = g_sum1[t]*inv;
        float var = g_sq1[t]*inv - mu*mu;
        float sc  = gamma1[t]*rsqrtf(var + EPSBN);
        sm.g.scs[t] = sc; sm.g.shs[t] = beta1[t] - mu*sc;
    }
    __syncthreads();
    // load h1 tile, BN1+ReLU, write y to LDS [64][132]
    {
        const float* hsrc = g_h1 + (size_t)((b*NN + nb)*16)*128;
        const int ch0 = (4*t) & 127;
        float4 sc4 = *(const float4*)&sm.g.scs[ch0];
        float4 sh4 = *(const float4*)&sm.g.shs[ch0];
        #pragma unroll
        for (int j=0;j<8;j++){
            int f = j*1024 + 4*t;
            float4 v = *(const float4*)&hsrc[f];
            int s = f >> 7;
            float4 yv;
            yv.x = fmaxf(0.f, fmaf(v.x, sc4.x, sh4.x));
            yv.y = fmaxf(0.f, fmaf(v.y, sc4.y, sh4.y));
            yv.z = fmaxf(0.f, fmaf(v.z, sc4.z, sh4.z));
            yv.w = fmaxf(0.f, fmaf(v.w, sc4.w, sh4.w));
            *(float4*)&sm.g.yls[s*132 + ch0] = yv;
        }
    }
    const int cg = t & 15, sg = t >> 4, w = t >> 6;
    float acc2[4][8];
    #pragma unroll
    for (int r=0;r<4;r++)
        #pragma unroll
        for (int c=0;c<8;c++) acc2[r][c]=0.f;
    for (int kc = 0; kc < 4; ++kc) {
        for (int e = t; e < 4096; e += 256) {     // stage W2[:, kc*32..+32) transposed, split A/B
            int d = e >> 5, kk = e & 31;
            float wv = W2[(d << 7) + (kc<<5) + kk];
            int cgd = d >> 3, h = d & 7;
            if (h < 4) ((float*)&sm.g.w2A[kk*16 + cgd])[h]   = wv;
            else       ((float*)&sm.g.w2B[kk*16 + cgd])[h-4] = wv;
        }
        __syncthreads();
        #pragma unroll
        for (int c4=0;c4<8;c4++){
            float4 wA[4], wB[4];
            #pragma unroll
            for (int ii=0;ii<4;ii++){ wA[ii] = sm.g.w2A[(4*c4+ii)*16 + cg]; wB[ii] = sm.g.w2B[(4*c4+ii)*16 + cg]; }
            #pragma unroll
            for (int r=0;r<4;r++){
                float4 yv = *(const float4*)&sm.g.yls[((sg<<2)+r)*132 + (kc<<5) + (c4<<2)];
                #pragma unroll
                for (int ii=0;ii<4;ii++){
                    float y = (ii==0)?yv.x:(ii==1)?yv.y:(ii==2)?yv.z:yv.w;
                    acc2[r][0] = fmaf(y, wA[ii].x, acc2[r][0]);
                    acc2[r][1] = fmaf(y, wA[ii].y, acc2[r][1]);
                    acc2[r][2] = fmaf(y, wA[ii].z, acc2[r][2]);
                    acc2[r][3] = fmaf(y, wA[ii].w, acc2[r][3]);
                    acc2[r][4] = fmaf(y, wB[ii].x, acc2[r][4]);
                    acc2[r][5] = fmaf(y, wB[ii].y, acc2[r][5]);
                    acc2[r][6] = fmaf(y, wB[ii].z, acc2[r][6]);
                    acc2[r][7] = fmaf(y, wB[ii].w, acc2[r][7]);
                }
            }
        }
        __syncthreads();
    }
    // epilogue: h2 = acc2 + b2 ; stats2 ; per-NODE min/max over 16 neighbors
    const int node = nb + (sg >> 2);
    #pragma unroll
    for (int c=0;c<8;c++){
        const int ch = (cg<<3)+c;
        const float bb = b2[ch];
        float ls=0.f, lq=0.f, mn=3e38f, mx=-3e38f;
        #pragma unroll
        for (int r=0;r<4;r++){
            float h2 = acc2[r][c] + bb;
            ls += h2; lq = fmaf(h2,h2,lq);
            mn = fminf(mn,h2); mx = fmaxf(mx,h2);
        }
        ls += __shfl_xor(ls,16); ls += __shfl_xor(ls,32);
        lq += __shfl_xor(lq,16); lq += __shfl_xor(lq,32);
        if ((sg & 3) == 0) { sm.g.redS[w*128 + ch] = ls; sm.g.redQ[w*128 + ch] = lq; }
        float o;
        o = __shfl_xor(mn,16); mn = fminf(mn,o);
        o = __shfl_xor(mn,32); mn = fminf(mn,o);
        o = __shfl_xor(mx,16); mx = fmaxf(mx,o);
        o = __shfl_xor(mx,32); mx = fmaxf(mx,o);
        if ((sg & 3) == 0) {
            const int oo = ((b<<12)+node)*128 + ch;
            g_hminN[oo] = mn; g_hmaxN[oo] = mx;
        }
    }
    __syncthreads();
    if (t < 128) {
        float s = sm.g.redS[t] + sm.g.redS[128+t] + sm.g.redS[256+t] + sm.g.redS[384+t];
        float q = sm.g.redQ[t] + sm.g.redQ[128+t] + sm.g.redQ[256+t] + sm.g.redQ[384+t];
        atomicAdd(&g_sum2[t], s);
        atomicAdd(&g_sq2[t], q);
    }
}

// ================= kFinal: gather centroid nodes, BN2 affine + ReLU via min/max monotonicity ==
__global__ __launch_bounds__(256) void kFinal(const float* __restrict__ gamma2, const float* __restrict__ beta2,
                                              float* __restrict__ out)
{
    const int gid = blockIdx.x*256 + threadIdx.x;
    const int base = gid << 2;
    const int sl = base >> 7;                 // global slot 0..4095
    const int b = sl >> 10, slot = sl & 1023;
    const int ch0 = base & 127;
    const int node = g_cent[b][slot];
    const int src = ((b<<12)+node)*128 + ch0;
    const float inv = 1.f/(float)M1TOT;
    float4 mx = *(const float4*)&g_hmaxN[src];
    float4 mn = *(const float4*)&g_hminN[src];
    float4 o;
    #pragma unroll
    for (int c=0;c<4;c++){
        int ch = ch0 + c;
        float mu = g_sum2[ch]*inv, var = g_sq2[ch]*inv - mu*mu;
        float sc = gamma2[ch]*rsqrtf(var+EPSBN), sh = beta2[ch] - mu*sc;
        float hi = (c==0)?mx.x:(c==1)?mx.y:(c==2)?mx.z:mx.w;
        float lo = (c==0)?mn.x:(c==1)?mn.y:(c==2)?mn.z:mn.w;
        float v = fmaxf(0.f, fmaf((sc >= 0.f) ? hi : lo, sc, sh));
        if (c==0) o.x=v; else if (c==1) o.y=v; else if (c==2) o.z=v; else o.w=v;
    }
    *(float4*)&out[12288 + base] = o;
}

extern "C" void kernel_launch(void* const* d_in, const int* in_sizes, int n_in,
                              void* d_out, int out_size, void* d_ws, size_t ws_size,
                              hipStream_t stream)
{
    (void)in_sizes; (void)n_in; (void)d_ws; (void)ws_size; (void)out_size;
    const float* feat = (const float*)d_in[0];
    const float* pos  = (const float*)d_in[1];
    const float* W1   = (const float*)d_in[2];
    const float* b1   = (const float*)d_in[3];
    const float* g1   = (const float*)d_in[4];
    const float* be1  = (const float*)d_in[5];
    const float* W2   = (const float*)d_in[6];
    const float* b2   = (const float*)d_in[7];
    const float* g2   = (const float*)d_in[8];
    const float* be2  = (const float*)d_in[9];
    float* out = (float*)d_out;

    kPre  <<<dim3(513),  dim3(256), 0, stream>>>(pos);
    kS1   <<<dim3(4100), dim3(256), 0, stream>>>(feat, pos, W1, b1);
    kS2   <<<dim3(4100), dim3(256), 0, stream>>>(pos, out, W2, b2, g1, be1);
    kFinal<<<dim3(512),  dim3(256), 0, stream>>>(g2, be2, out);
}

// Round 12
// 1427.027 us; speedup vs baseline: 1.6832x; 1.0298x over previous
//
#include <hip/hip_runtime.h>

typedef float f2 __attribute__((ext_vector_type(2)));

#define NB 4
#define NN 4096
#define KNB 16
#define NS 1024
#define M1TOT (NB*NN*KNB)   // 262144
#define EPSBN 1e-5f
#define FPS_SPLIT 511       // kS1 runs iters [0,511); kS2 runs [511,1023)
#define PADN 4124           // 4096 + 4 pad per 512-chunk: conflict-free 8-chunk parallel scan

// ---- module-scope scratch (fully rewritten every call; no ws_size assumption)
__device__ __align__(16) int   g_nbr[NB*NN*KNB];
__device__ __align__(16) float g_fps_rd[NB][NN];
__device__ unsigned g_fps_sel[NB][256];
__device__ int   g_fps_last[NB];
__device__ int   g_cent[NB][NS];
__device__ float g_sum1[128], g_sq1[128], g_sum2[128], g_sq2[128];
__device__ __align__(16) float g_hminN[NB*NN*128];        // 8 MB per-node h2 min
__device__ __align__(16) float g_hmaxN[NB*NN*128];        // 8 MB per-node h2 max

struct __align__(16) FpsSm {
    float spx[NN], spy[NN], spz[NN];
    float sv[2][4]; int sj[2][4];
    int   cnts[256];
};
// sb float layout, phase 1 (both kS1 and kS2): x@0 [64*68], W1A@4352 [68*64], W1B@8704 [68*64]
// kS2 phase 2 reuse:                          y@0 [64*132], W2A@8448 [2048], W2B@10496 [2048]
struct __align__(16) G1Sm {
    float sb[13056];
    float redS[512], redQ[512];
};
struct __align__(16) G2Sm {
    float sb[13056];
    float scs[128], shs[128];
    float redS[512], redQ[512];
};
// kPre scan phase: padded point cache (49.5KB); merge phase reuses LDS for keys (stride 130)
union KnnSm {
    struct { float spx[PADN], spy[PADN], spz[PADN]; } p;
    unsigned long long pairs[32*130];
};

// ================= FPS chunk: 256 threads, 16 pts/thread (f2 packed), checkpointed ==========
__device__ __forceinline__ void fps_chunk(const float* __restrict__ pos, float* __restrict__ out,
                                          FpsSm* sm, int b, int t, int it0, int it1,
                                          bool first, bool last)
{
#pragma clang fp contract(off)
    const float* pb = pos + b*NN*3;
    for (int i = t; i < NN; i += 256) { sm->spx[i]=pb[3*i]; sm->spy[i]=pb[3*i+1]; sm->spz[i]=pb[3*i+2]; }
    __syncthreads();
    f2 rx[8], ry[8], rz[8], rd[8];
    #pragma unroll
    for (int p=0;p<8;p++){
        int j = (t<<4) + 2*p;
        rx[p] = *(const f2*)&sm->spx[j];
        ry[p] = *(const f2*)&sm->spy[j];
        rz[p] = *(const f2*)&sm->spz[j];
    }
    unsigned sel; int j2;
    if (first) {
        #pragma unroll
        for (int p=0;p<8;p++) rd[p] = (f2){1e10f, 1e10f};
        sel = (t==0) ? 1u : 0u;              // node 0 is always selected
        j2 = 0;
    } else {
        #pragma unroll
        for (int u=0;u<4;u++){
            float4 ld = *(const float4*)&g_fps_rd[b][(t<<4)+(u<<2)];
            rd[2*u]   = (f2){ld.x, ld.y};
            rd[2*u+1] = (f2){ld.z, ld.w};
        }
        sel = g_fps_sel[b][t];
        j2  = g_fps_last[b];
    }
    float cx = sm->spx[j2], cy = sm->spy[j2], cz = sm->spz[j2];

    for (int it = it0; it < it1; ++it) {
        const int par = it & 1;
        const f2 c2x = {cx,cx}, c2y = {cy,cy}, c2z = {cz,cz};
        #pragma unroll
        for (int p=0;p<8;p++){
            f2 dx = rx[p]-c2x, dy = ry[p]-c2y, dz = rz[p]-c2z;
            f2 m0 = dx*dx, m1 = dy*dy, m2 = dz*dz;
            f2 a0 = m0 + m1;
            f2 d  = a0 + m2;                 // exact (dx^2+dy^2)+dz^2, contract off
            rd[p] = __builtin_elementwise_min(rd[p], d);
        }
        // local max tree (packed)
        f2 t0 = __builtin_elementwise_max(rd[0], rd[1]);
        f2 t1 = __builtin_elementwise_max(rd[2], rd[3]);
        f2 t2 = __builtin_elementwise_max(rd[4], rd[5]);
        f2 t3 = __builtin_elementwise_max(rd[6], rd[7]);
        t0 = __builtin_elementwise_max(t0, t1);
        t2 = __builtin_elementwise_max(t2, t3);
        t0 = __builtin_elementwise_max(t0, t2);
        float wv = fmaxf(t0.x, t0.y);
        // wave max, value only (6 cross-lane ops)
        #pragma unroll
        for (int m=1;m<64;m<<=1) wv = fmaxf(wv, __shfl_xor(wv, m));
        // lowest local index equal to wave max (reverse scan -> lowest wins)
        int lj = 0x7fffffff;
        #pragma unroll
        for (int p=7;p>=0;p--){
            lj = (rd[p].y == wv) ? ((t<<4)+2*p+1) : lj;
            lj = (rd[p].x == wv) ? ((t<<4)+2*p)   : lj;
        }
        // lanes cover ascending index ranges: first matching lane = lowest global index
        unsigned long long mk = __ballot(lj != 0x7fffffff);
        int src = __ffsll(mk) - 1;
        int bj = __shfl(lj, src);
        if ((t & 63) == 0) { sm->sv[par][t>>6] = wv; sm->sj[par][t>>6] = bj; }
        __syncthreads();     // single barrier/iter; parity double-buffered slots
        float v = sm->sv[par][0]; int jn = sm->sj[par][0];
        #pragma unroll
        for (int w=1;w<4;w++){
            float ov = sm->sv[par][w]; int oj = sm->sj[par][w];
            if (ov > v || (ov == v && oj < jn)) { v = ov; jn = oj; }
        }
        j2 = jn;
        cx = sm->spx[j2]; cy = sm->spy[j2]; cz = sm->spz[j2];
        unsigned rel = (unsigned)(j2 - (t<<4));
        if (rel < 16u) sel |= (1u << rel);
    }

    if (!last) {
        #pragma unroll
        for (int u=0;u<4;u++){
            float4 st = {rd[2*u].x, rd[2*u].y, rd[2*u+1].x, rd[2*u+1].y};
            *(float4*)&g_fps_rd[b][(t<<4)+(u<<2)] = st;
        }
        g_fps_sel[b][t] = sel;
        if (t == 0) g_fps_last[b] = j2;
    } else {
        // ordered compaction (ascending node index == reference's sorted centroids)
        sm->cnts[t] = (int)__popc(sel);
        __syncthreads();
        if (t == 0) { int run = 0; for (int i=0;i<256;i++){ int c = sm->cnts[i]; sm->cnts[i] = run; run += c; } }
        __syncthreads();
        int base = sm->cnts[t];
        #pragma unroll
        for (int i=0;i<16;i++){
            int j = (t<<4)+i;
            if (sel & (1u<<i)) {
                g_cent[b][base] = j;
                float* po = out + (size_t)((b<<10)+base)*3;
                po[0]=sm->spx[j]; po[1]=sm->spy[j]; po[2]=sm->spz[j];
                base++;
            }
        }
    }
}

// u64 insert for the merge phase (key = dist_bits<<32 | idx, total order == (d, idx))
__device__ __forceinline__ void key_ins(unsigned long long (&kk)[16], unsigned long long &wmax,
                                        unsigned long long key)
{
    unsigned long long m0 = kk[0]; int mj = 0;
    #pragma unroll
    for (int u=1;u<16;u++){ if (kk[u] > m0){ m0 = kk[u]; mj = u; } }
    #pragma unroll
    for (int u=0;u<16;u++){ if (u == mj) kk[u] = key; }
    unsigned long long w = kk[0];
    #pragma unroll
    for (int u=1;u<16;u++) w = (kk[u] > w) ? kk[u] : w;
    wmax = w;
}

// ===== kPre: blocks 0-511 split-scan KNN (8 lanes/query, 32 queries/block), block 512 zero ===
__global__ __launch_bounds__(256, 1) void kPre(const float* __restrict__ pos)
{
    __shared__ KnnSm sm;
    const int blk = blockIdx.x, t = threadIdx.x;
    if (blk >= 512) {
        if (t < 128) { g_sum1[t]=0.f; g_sq1[t]=0.f; g_sum2[t]=0.f; g_sq2[t]=0.f; }
        return;
    }
    const int b = blk >> 7;                    // 128 blocks per batch
    const int qloc = t >> 3, tq = t & 7;
    const int q = ((blk & 127) << 5) + qloc;
    const float* pb = pos + b*NN*3;
    for (int i = t; i < NN; i += 256) {
        int l = i + ((i >> 9) << 2);           // padded slot
        sm.p.spx[l]=pb[3*i]; sm.p.spy[l]=pb[3*i+1]; sm.p.spz[l]=pb[3*i+2];
    }
    __syncthreads();
    const int lq = q + ((q >> 9) << 2);
    const float qx = sm.p.spx[lq], qy = sm.p.spy[lq], qz = sm.p.spz[lq];
    float bd[16]; int bi[16];
    #pragma unroll
    for (int u=0;u<16;u++){ bd[u]=3e38f; bi[u]=0; }
    float wmax = 3e38f;
    const int base = tq * 516;                 // padded chunk base: banks (4*tq+i)%32, distinct
    const int j0 = tq << 9;
    for (int i = 0; i < 512; ++i) {
        float dx = sm.p.spx[base+i]-qx, dy = sm.p.spy[base+i]-qy, dz = sm.p.spz[base+i]-qz;
        float d = __fadd_rn(__fadd_rn(__fmul_rn(dx,dx),__fmul_rn(dy,dy)),__fmul_rn(dz,dz));
        if (d < wmax) {                        // strict <: lowest j wins boundary ties
            float m0 = bd[0]; int mj = 0;
            #pragma unroll
            for (int u=1;u<16;u++){ if (bd[u] > m0) { m0 = bd[u]; mj = u; } }
            #pragma unroll
            for (int u=0;u<16;u++){ if (u == mj) { bd[u] = d; bi[u] = j0 + i; } }
            wmax = bd[0];
            #pragma unroll
            for (int u=1;u<16;u++) wmax = fmaxf(wmax, bd[u]);
        }
    }
    __syncthreads();                           // scan done; LDS points no longer needed
    #pragma unroll
    for (int u=0;u<16;u++)
        sm.pairs[qloc*130 + (tq<<4) + u] =
            ((unsigned long long)__float_as_uint(bd[u]) << 32) | (unsigned)bi[u];
    __syncthreads();
    if (tq == 0) {                             // merge 128 partial keys -> exact global top-16
        unsigned long long kk2[16];
        #pragma unroll
        for (int u=0;u<16;u++) kk2[u] = ~0ULL;
        unsigned long long wm2 = ~0ULL;
        for (int e = 0; e < 128; ++e) {
            unsigned long long key = sm.pairs[qloc*130 + e];
            if (key < wm2) key_ins(kk2, wm2, key);
        }
        int* dst = g_nbr + ((size_t)(b*NN + q) << 4);
        #pragma unroll
        for (int u=0;u<16;u++) dst[u] = (int)(kk2[u] & 0xffffffffu);
    }
}

// ===== shared: stage W1 (dest-major, conflict-free) + gather x + GEMM1 -> acc[4][8] =========
// thread roles: cg = t&15 -> channels 8cg..8cg+7 ; sg = t>>4 -> samples sg+16r (r=0..3)
__device__ __forceinline__ void w1_gather_gemm1(const float* __restrict__ feat,
        const float* __restrict__ pos, const float* __restrict__ W1,
        float* __restrict__ sb, int b, int nb, int t, float acc[4][8])
{
    float* wAf = sb + 4352;
    float* wBf = sb + 8704;
    // dest-major staging: lane writes consecutive LDS floats (conflict-free);
    // W1 (34KB) is L2-resident so the scattered source reads are cheap.
    for (int a = t; a < 4352; a += 256) {
        int row = a >> 6, cgd = (a >> 2) & 15, h = a & 3;
        int coA = (cgd << 3) + h;
        int ci  = (row < 64) ? (row + 3) : (row - 64);   // x rows: feat 0..63, rel 64..66, 67 pad
        float vA = (row < 67) ? W1[coA * 67 + ci] : 0.f;
        float vB = (row < 67) ? W1[(coA + 4) * 67 + ci] : 0.f;
        wAf[a] = vA; wBf[a] = vB;
    }
    {
        const int s = t >> 2, h = t & 3;
        const int n = nb + (s >> 4), k = s & 15;
        const int gq = b*NN + n;
        const int idx = g_nbr[(gq << 4) + k];
        const float* fr = feat + ((size_t)(b*NN + idx) << 6) + (h << 4);
        float* xr = sb + s*68 + (h << 4);
        #pragma unroll
        for (int u=0;u<4;u++) ((float4*)xr)[u] = ((const float4*)fr)[u];
        if (h == 0) {
            const float* pn = pos + (size_t)gq*3;
            const float* pi = pos + (size_t)(b*NN + idx)*3;
            sb[s*68 + 64] = pi[0]-pn[0];
            sb[s*68 + 65] = pi[1]-pn[1];
            sb[s*68 + 66] = pi[2]-pn[2];
            sb[s*68 + 67] = 0.f;
        }
    }
    __syncthreads();
    const int cg = t & 15, sg = t >> 4;
    const float4* wA4 = (const float4*)wAf;
    const float4* wB4 = (const float4*)wBf;
    #pragma unroll
    for (int r=0;r<4;r++)
        #pragma unroll
        for (int c=0;c<8;c++) acc[r][c] = 0.f;
    for (int c4 = 0; c4 < 17; ++c4) {
        float4 wA[4], wB[4];
        #pragma unroll
        for (int ii=0;ii<4;ii++){ wA[ii] = wA4[(4*c4+ii)*16 + cg]; wB[ii] = wB4[(4*c4+ii)*16 + cg]; }
        #pragma unroll
        for (int r=0;r<4;r++){
            float4 xv = *(const float4*)&sb[(sg + (r<<4))*68 + (c4<<2)];
            #pragma unroll
            for (int ii=0;ii<4;ii++){
                float x = (ii==0)?xv.x:(ii==1)?xv.y:(ii==2)?xv.z:xv.w;
                acc[r][0] = fmaf(x, wA[ii].x, acc[r][0]);
                acc[r][1] = fmaf(x, wA[ii].y, acc[r][1]);
                acc[r][2] = fmaf(x, wA[ii].z, acc[r][2]);
                acc[r][3] = fmaf(x, wA[ii].w, acc[r][3]);
                acc[r][4] = fmaf(x, wB[ii].x, acc[r][4]);
                acc[r][5] = fmaf(x, wB[ii].y, acc[r][5]);
                acc[r][6] = fmaf(x, wB[ii].z, acc[r][6]);
                acc[r][7] = fmaf(x, wB[ii].w, acc[r][7]);
            }
        }
    }
}

// ================= kS1: blocks 0-3 FPS [0,511); blocks 4..4099 GEMM1 stats only ==============
__global__ __launch_bounds__(256, 1) void kS1(const float* __restrict__ feat, const float* __restrict__ pos,
                                              const float* __restrict__ W1, const float* __restrict__ b1)
{
    __shared__ union { FpsSm f; G1Sm g; } sm;
    const int blk = blockIdx.x, t = threadIdx.x;
    if (blk < 4) { fps_chunk(pos, nullptr, &sm.f, blk, t, 0, FPS_SPLIT, true, false); return; }
    const int gb = blk - 4;
    const int b = gb >> 10, nb = (gb & 1023) << 2;
    float acc[4][8];
    w1_gather_gemm1(feat, pos, W1, sm.g.sb, b, nb, t, acc);
    const int cg = t & 15, sg = t >> 4, w = t >> 6;
    float4 bA = *(const float4*)&b1[cg<<3];
    float4 bB = *(const float4*)&b1[(cg<<3)+4];
    #pragma unroll
    for (int c=0;c<8;c++){
        const int ch = (cg<<3)+c;
        const float bb = (c<4) ? ((c==0)?bA.x:(c==1)?bA.y:(c==2)?bA.z:bA.w)
                               : ((c==4)?bB.x:(c==5)?bB.y:(c==6)?bB.z:bB.w);
        float ls=0.f, lq=0.f;
        #pragma unroll
        for (int r=0;r<4;r++){ float h1 = acc[r][c] + bb; ls += h1; lq = fmaf(h1,h1,lq); }
        ls += __shfl_xor(ls,16); ls += __shfl_xor(ls,32);
        lq += __shfl_xor(lq,16); lq += __shfl_xor(lq,32);
        if ((sg & 3) == 0) { sm.g.redS[w*128 + ch] = ls; sm.g.redQ[w*128 + ch] = lq; }
    }
    __syncthreads();
    if (t < 128) {
        float s = sm.g.redS[t] + sm.g.redS[128+t] + sm.g.redS[256+t] + sm.g.redS[384+t];
        float q = sm.g.redQ[t] + sm.g.redQ[128+t] + sm.g.redQ[256+t] + sm.g.redQ[384+t];
        atomicAdd(&g_sum1[t], s);
        atomicAdd(&g_sq1[t], q);
    }
}

// ===== kS2: blocks 0-3 FPS finish; blocks 4..4099 recompute GEMM1 + BN1 + GEMM2 + stats2 =====
__global__ __launch_bounds__(256, 1) void kS2(const float* __restrict__ feat, const float* __restrict__ pos,
        float* __restrict__ out, const float* __restrict__ W1, const float* __restrict__ b1,
        const float* __restrict__ gamma1, const float* __restrict__ beta1,
        const float* __restrict__ W2, const float* __restrict__ b2)
{
    __shared__ union { FpsSm f; G2Sm g; } sm;
    const int blk = blockIdx.x, t = threadIdx.x;
    if (blk < 4) { fps_chunk(pos, out, &sm.f, blk, t, FPS_SPLIT, NS-1, false, true); return; }
    const int gb = blk - 4;
    const int b = gb >> 10, nb = (gb & 1023) << 2;
    if (t < 128) {
        const float inv = 1.f/(float)M1TOT;
        float mu  = g_sum1[t]*inv;
        float var = g_sq1[t]*inv - mu*mu;
        float sc  = gamma1[t]*rsqrtf(var + EPSBN);
        sm.g.scs[t] = sc; sm.g.shs[t] = beta1[t] - mu*sc;
    }
    float acc[4][8];
    w1_gather_gemm1(feat, pos, W1, sm.g.sb, b, nb, t, acc);  // barrier inside covers scs too
    const int cg = t & 15, sg = t >> 4, w = t >> 6;
    __syncthreads();                       // all phase-1 LDS reads done before overwrite
    // BN1 + ReLU -> y in LDS [64][132] (float4 writes)
    {
        float4 bA = *(const float4*)&b1[cg<<3];
        float4 bB = *(const float4*)&b1[(cg<<3)+4];
        float4 scA = *(const float4*)&sm.g.scs[cg<<3];
        float4 scB = *(const float4*)&sm.g.scs[(cg<<3)+4];
        float4 shA = *(const float4*)&sm.g.shs[cg<<3];
        float4 shB = *(const float4*)&sm.g.shs[(cg<<3)+4];
        #pragma unroll
        for (int r=0;r<4;r++){
            const int s = sg + (r<<4);
            float4 y0, y1;
            y0.x = fmaxf(0.f, fmaf(acc[r][0]+bA.x, scA.x, shA.x));
            y0.y = fmaxf(0.f, fmaf(acc[r][1]+bA.y, scA.y, shA.y));
            y0.z = fmaxf(0.f, fmaf(acc[r][2]+bA.z, scA.z, shA.z));
            y0.w = fmaxf(0.f, fmaf(acc[r][3]+bA.w, scA.w, shA.w));
            y1.x = fmaxf(0.f, fmaf(acc[r][4]+bB.x, scB.x, shB.x));
            y1.y = fmaxf(0.f, fmaf(acc[r][5]+bB.y, scB.y, shB.y));
            y1.z = fmaxf(0.f, fmaf(acc[r][6]+bB.z, scB.z, shB.z));
            y1.w = fmaxf(0.f, fmaf(acc[r][7]+bB.w, scB.w, shB.w));
            *(float4*)&sm.g.sb[s*132 + (cg<<3)]     = y0;
            *(float4*)&sm.g.sb[s*132 + (cg<<3) + 4] = y1;
        }
    }
    float* w2Af = sm.g.sb + 8448;
    float* w2Bf = sm.g.sb + 10496;
    float acc2[4][8];
    #pragma unroll
    for (int r=0;r<4;r++)
        #pragma unroll
        for (int c=0;c<8;c++) acc2[r][c]=0.f;
    for (int kc = 0; kc < 4; ++kc) {
        // dest-major W2 staging (conflict-free LDS writes; W2 64KB is L2-resident)
        for (int a = t; a < 2048; a += 256) {
            int kk = a >> 6, cgd = (a >> 2) & 15, h = a & 3;
            int dA = (cgd << 3) + h;
            w2Af[a] = W2[(dA << 7) + (kc << 5) + kk];
            w2Bf[a] = W2[((dA + 4) << 7) + (kc << 5) + kk];
        }
        __syncthreads();
        const float4* w2A4 = (const float4*)w2Af;
        const float4* w2B4 = (const float4*)w2Bf;
        #pragma unroll
        for (int c4=0;c4<8;c4++){
            float4 wA[4], wB[4];
            #pragma unroll
            for (int ii=0;ii<4;ii++){ wA[ii] = w2A4[(4*c4+ii)*16 + cg]; wB[ii] = w2B4[(4*c4+ii)*16 + cg]; }
            #pragma unroll
            for (int r=0;r<4;r++){
                float4 yv = *(const float4*)&sm.g.sb[((sg<<2)+r)*132 + (kc<<5) + (c4<<2)];
                #pragma unroll
                for (int ii=0;ii<4;ii++){
                    float y = (ii==0)?yv.x:(ii==1)?yv.y:(ii==2)?yv.z:yv.w;
                    acc2[r][0] = fmaf(y, wA[ii].x, acc2[r][0]);
                    acc2[r][1] = fmaf(y, wA[ii].y, acc2[r][1]);
                    acc2[r][2] = fmaf(y, wA[ii].z, acc2[r][2]);
                    acc2[r][3] = fmaf(y, wA[ii].w, acc2[r][3]);
                    acc2[r][4] = fmaf(y, wB[ii].x, acc2[r][4]);
                    acc2[r][5] = fmaf(y, wB[ii].y, acc2[r][5]);
                    acc2[r][6] = fmaf(y, wB[ii].z, acc2[r][6]);
                    acc2[r][7] = fmaf(y, wB[ii].w, acc2[r][7]);
                }
            }
        }
        __syncthreads();
    }
    // epilogue: h2 = acc2 + b2 ; stats2 ; per-NODE min/max over 16 neighbors
    const int node = nb + (sg >> 2);
    #pragma unroll
    for (int c=0;c<8;c++){
        const int ch = (cg<<3)+c;
        const float bb = b2[ch];
        float ls=0.f, lq=0.f, mn=3e38f, mx=-3e38f;
        #pragma unroll
        for (int r=0;r<4;r++){
            float h2 = acc2[r][c] + bb;
            ls += h2; lq = fmaf(h2,h2,lq);
            mn = fminf(mn,h2); mx = fmaxf(mx,h2);
        }
        ls += __shfl_xor(ls,16); ls += __shfl_xor(ls,32);
        lq += __shfl_xor(lq,16); lq += __shfl_xor(lq,32);
        if ((sg & 3) == 0) { sm.g.redS[w*128 + ch] = ls; sm.g.redQ[w*128 + ch] = lq; }
        float o;
        o = __shfl_xor(mn,16); mn = fminf(mn,o);
        o = __shfl_xor(mn,32); mn = fminf(mn,o);
        o = __shfl_xor(mx,16); mx = fmaxf(mx,o);
        o = __shfl_xor(mx,32); mx = fmaxf(mx,o);
        if ((sg & 3) == 0) {
            const int oo = ((b<<12)+node)*128 + ch;
            g_hminN[oo] = mn; g_hmaxN[oo] = mx;
        }
    }
    __syncthreads();
    if (t < 128) {
        float s = sm.g.redS[t] + sm.g.redS[128+t] + sm.g.redS[256+t] + sm.g.redS[384+t];
        float q = sm.g.redQ[t] + sm.g.redQ[128+t] + sm.g.redQ[256+t] + sm.g.redQ[384+t];
        atomicAdd(&g_sum2[t], s);
        atomicAdd(&g_sq2[t], q);
    }
}

// ================= kFinal: gather centroid nodes, BN2 affine + ReLU via min/max monotonicity ==
__global__ __launch_bounds__(256) void kFinal(const float* __restrict__ gamma2, const float* __restrict__ beta2,
                                              float* __restrict__ out)
{
    const int gid = blockIdx.x*256 + threadIdx.x;
    const int base = gid << 2;
    const int sl = base >> 7;                 // global slot 0..4095
    const int b = sl >> 10, slot = sl & 1023;
    const int ch0 = base & 127;
    const int node = g_cent[b][slot];
    const int src = ((b<<12)+node)*128 + ch0;
    const float inv = 1.f/(float)M1TOT;
    float4 mx = *(const float4*)&g_hmaxN[src];
    float4 mn = *(const float4*)&g_hminN[src];
    float4 o;
    #pragma unroll
    for (int c=0;c<4;c++){
        int ch = ch0 + c;
        float mu = g_sum2[ch]*inv, var = g_sq2[ch]*inv - mu*mu;
        float sc = gamma2[ch]*rsqrtf(var+EPSBN), sh = beta2[ch] - mu*sc;
        float hi = (c==0)?mx.x:(c==1)?mx.y:(c==2)?mx.z:mx.w;
        float lo = (c==0)?mn.x:(c==1)?mn.y:(c==2)?mn.z:mn.w;
        float v = fmaxf(0.f, fmaf((sc >= 0.f) ? hi : lo, sc, sh));
        if (c==0) o.x=v; else if (c==1) o.y=v; else if (c==2) o.z=v; else o.w=v;
    }
    *(float4*)&out[12288 + base] = o;
}

extern "C" void kernel_launch(void* const* d_in, const int* in_sizes, int n_in,
                              void* d_out, int out_size, void* d_ws, size_t ws_size,
                              hipStream_t stream)
{
    (void)in_sizes; (void)n_in; (void)d_ws; (void)ws_size; (void)out_size;
    const float* feat = (const float*)d_in[0];
    const float* pos  = (const float*)d_in[1];
    const float* W1   = (const float*)d_in[2];
    const float* b1   = (const float*)d_in[3];
    const float* g1   = (const float*)d_in[4];
    const float* be1  = (const float*)d_in[5];
    const float* W2   = (const float*)d_in[6];
    const float* b2   = (const float*)d_in[7];
    const float* g2   = (const float*)d_in[8];
    const float* be2  = (const float*)d_in[9];
    float* out = (float*)d_out;

    kPre  <<<dim3(513),  dim3(256), 0, stream>>>(pos);
    kS1   <<<dim3(4100), dim3(256), 0, stream>>>(feat, pos, W1, b1);
    kS2   <<<dim3(4100), dim3(256), 0, stream>>>(feat, pos, out, W1, b1, g1, be1, W2, b2);
    kFinal<<<dim3(512),  dim3(256), 0, stream>>>(g2, be2, out);
}